// Round 1
// baseline (72.553 us; speedup 1.0000x reference)
//
#include <hip/hip_runtime.h>
#include <stdint.h>

// Grouped linear: y[z] = coeff * x[z] @ W[idx[z]], idx sorted.
// C=8, U=V=512, Z=32768, fp32 in/out, bf16 MFMA compute.

#define Cg 8
#define Ud 512
#define Vd 512
#define Zd 32768

#define BM 128
#define BN 128
#define BK 32
#define NKT (Ud / BK)  // 16

typedef __attribute__((ext_vector_type(8))) short bf16x8;
typedef __attribute__((ext_vector_type(4))) float f32x4;
typedef __attribute__((ext_vector_type(4))) unsigned short us4;
typedef __attribute__((ext_vector_type(4))) float float4v;

__device__ __forceinline__ unsigned short f2bf(float f) {
    unsigned int u = __float_as_uint(f);
    u += 0x7fffu + ((u >> 16) & 1u);   // round-to-nearest-even
    return (unsigned short)(u >> 16);
}

__global__ __launch_bounds__(256, 2)
void sgl_kernel(const float* __restrict__ w, const float* __restrict__ x,
                const int* __restrict__ idx, const float* __restrict__ coeff,
                float* __restrict__ y)
{
    // Subtiled LDS layout: element (r,k) at ushort offset
    //   (r>>4)*512 + (k>>3)*128 + (r&15)*8 + (k&7)
    // -> each lane's 8 k-consecutive frag elements are one aligned 16B read,
    //    16-lane groups cover all 32 banks (conflict-free ds_read_b128).
    __shared__ unsigned short As[BM * BK];  // 8 KiB
    __shared__ unsigned short Bs[BN * BK];  // 8 KiB

    const int tid  = threadIdx.x;
    const int bn   = blockIdx.x & 3;        // Vd/BN = 4
    const int bm   = blockIdx.x >> 2;
    const int row0 = bm * BM;
    const int col0 = bn * BN;

    const int lane = tid & 63;
    const int wave = tid >> 6;
    const int wr   = (wave >> 1) * 64;      // wave row offset in tile
    const int wc   = (wave & 1) * 64;       // wave col offset in tile
    const int l15  = lane & 15;
    const int l4   = lane >> 4;

    // A-staging task geometry (constant across k-tiles): 4 tasks/thread,
    // task i: row ar[i], k-offset ak[i] (4 floats -> 4 bf16, one 8B LDS write)
    int ar[4], ak[4], ag[4];
#pragma unroll
    for (int i = 0; i < 4; ++i) {
        int flat = tid + i * 256;
        ar[i] = flat >> 3;                  // 0..127
        ak[i] = (flat & 7) << 2;            // 0,4,...,28
        ag[i] = idx[row0 + ar[i]];          // group of this row
    }

    const int g_lo = idx[row0];
    const int g_hi = idx[row0 + BM - 1];

    f32x4 acc[4][4];
#pragma unroll
    for (int mi = 0; mi < 4; ++mi)
#pragma unroll
        for (int ni = 0; ni < 4; ++ni)
            acc[mi][ni] = f32x4{0.f, 0.f, 0.f, 0.f};

    for (int g = g_lo; g <= g_hi; ++g) {    // 1 pass except at group boundaries
        const float* __restrict__ Wg = w + (size_t)g * ((size_t)Ud * Vd);
        for (int kt = 0; kt < NKT; ++kt) {
            __syncthreads();                // prior reads done before overwrite
            // ---- stage A: x tile, group-masked, fp32 -> bf16 ----
#pragma unroll
            for (int i = 0; i < 4; ++i) {
                const float4v v = *(const float4v*)(x + (size_t)(row0 + ar[i]) * Ud
                                                      + kt * BK + ak[i]);
                const bool ok = (ag[i] == g);
                us4 p;
                p[0] = f2bf(ok ? v[0] : 0.0f);
                p[1] = f2bf(ok ? v[1] : 0.0f);
                p[2] = f2bf(ok ? v[2] : 0.0f);
                p[3] = f2bf(ok ? v[3] : 0.0f);
                const int off = ((ar[i] >> 4) << 9) | ((ak[i] >> 3) << 7)
                              | ((ar[i] & 15) << 3) | (ak[i] & 7);
                *(us4*)(As + off) = p;
            }
            // ---- stage B: W[g] tile, transposed into [n][k] subtiles ----
            // thread task: column n, k-range k0..k0+3 (4 coalesced dword loads)
#pragma unroll
            for (int i = 0; i < 4; ++i) {
                const int flat = tid + i * 256;
                const int n  = flat & 127;
                const int k0 = (flat >> 7) << 2;    // 0,4,...,28
                const float* src = Wg + (size_t)(kt * BK + k0) * Vd + col0 + n;
                us4 p;
                p[0] = f2bf(src[0]);
                p[1] = f2bf(src[Vd]);
                p[2] = f2bf(src[2 * Vd]);
                p[3] = f2bf(src[3 * Vd]);
                const int off = ((n >> 4) << 9) | ((k0 >> 3) << 7)
                              | ((n & 15) << 3) | (k0 & 7);
                *(us4*)(Bs + off) = p;
            }
            __syncthreads();
            // ---- fragments + MFMA (one 16x16x32 consumes full BK) ----
            bf16x8 a[4], b[4];
#pragma unroll
            for (int mi = 0; mi < 4; ++mi) {
                const int r = wr + mi * 16;
                a[mi] = *(const bf16x8*)(As + ((r >> 4) << 9) + (l4 << 7) + (l15 << 3));
            }
#pragma unroll
            for (int ni = 0; ni < 4; ++ni) {
                const int c = wc + ni * 16;
                b[ni] = *(const bf16x8*)(Bs + ((c >> 4) << 9) + (l4 << 7) + (l15 << 3));
            }
#pragma unroll
            for (int mi = 0; mi < 4; ++mi)
#pragma unroll
                for (int ni = 0; ni < 4; ++ni)
                    acc[mi][ni] = __builtin_amdgcn_mfma_f32_16x16x32_bf16(
                        a[mi], b[ni], acc[mi][ni], 0, 0, 0);
        }
    }

    // ---- epilogue: C/D layout col=lane&15, row=(lane>>4)*4+q (m89) ----
    const float cf = coeff[0];
#pragma unroll
    for (int mi = 0; mi < 4; ++mi) {
        const int rbase = row0 + wr + mi * 16 + l4 * 4;
#pragma unroll
        for (int ni = 0; ni < 4; ++ni) {
            const int c = col0 + wc + ni * 16 + l15;
#pragma unroll
            for (int q = 0; q < 4; ++q) {
                y[(size_t)(rbase + q) * Vd + c] = acc[mi][ni][q] * cf;
            }
        }
    }
}

extern "C" void kernel_launch(void* const* d_in, const int* in_sizes, int n_in,
                              void* d_out, int out_size, void* d_ws, size_t ws_size,
                              hipStream_t stream) {
    const float* w     = (const float*)d_in[0];
    const float* x     = (const float*)d_in[1];
    const int*   idx   = (const int*)d_in[2];
    const float* coeff = (const float*)d_in[3];
    float* y = (float*)d_out;

    dim3 grid((Zd / BM) * (Vd / BN));   // 256 * 4 = 1024 blocks
    dim3 block(256);
    hipLaunchKernelGGL(sgl_kernel, grid, block, 0, stream, w, x, idx, coeff, y);
}

// Round 2
// 70.503 us; speedup vs baseline: 1.0291x; 1.0291x over previous
//
#include <hip/hip_runtime.h>
#include <stdint.h>

// Grouped linear: y[z] = coeff * x[z] @ W[idx[z]], idx sorted.
// C=8, U=V=512, Z=32768, fp32 in/out, bf16 MFMA compute.
//
// R2 strategy: pre-convert x and W to bf16 into d_ws, already laid out in
// LDS subtile order, so the GEMM stages with global_load_lds (width 16,
// linear copy) and reads conflict-free ds_read_b128 fragments.

#define Cg 8
#define Ud 512
#define Vd 512
#define Zd 32768

#define BM 128
#define BN 128
#define BK 64
#define KT (Ud / BK)          // 8 k-tiles
#define TILE_US (BM * BK)     // 8192 ushorts = 16 KiB per tile

#define NBM (Zd / BM)         // 256
#define NBN (Vd / BN)         // 4
#define WSX_TILES (NBM * KT)                  // 2048 tiles (32 MiB)
#define WSW_TILES (Cg * NBN * KT)             // 256 tiles (4 MiB)
#define WS_NEEDED ((size_t)(WSX_TILES + WSW_TILES) * TILE_US * 2)

typedef __attribute__((ext_vector_type(8))) short bf16x8;
typedef __attribute__((ext_vector_type(4))) float f32x4;
typedef __attribute__((ext_vector_type(4))) unsigned short us4;
typedef __attribute__((ext_vector_type(4))) float float4v;

typedef __attribute__((address_space(3))) unsigned int lds_uint;
typedef const __attribute__((address_space(1))) unsigned int gbl_uint;

__device__ __forceinline__ unsigned short f2bf(float f) {
    unsigned int u = __float_as_uint(f);
    u += 0x7fffu + ((u >> 16) & 1u);   // round-to-nearest-even
    return (unsigned short)(u >> 16);
}

// Subtile layout within one [BM rows][BK k] tile (ushort offset):
//   (r>>4)*1024 + (k>>3)*128 + (r&15)*8 + (k&7)
// Fragment read for 16x16x32 MFMA: lane l -> r=l&15, k=(l>>4)*8 (+kk*32):
// byte addr = rt*2048 + (kk*4+l4)*256 + l15*16 -> 16-lane groups stride 16B,
// conflict-free ds_read_b128.
__device__ __forceinline__ int sub_off(int r, int k) {
    return ((r >> 4) << 10) + ((k >> 3) << 7) + ((r & 15) << 3) + (k & 7);
}

// ---------------- converters ----------------

__global__ __launch_bounds__(256)
void convert_x(const float* __restrict__ x, unsigned short* __restrict__ wsx)
{
    const int ntask = Zd * Ud / 4;           // one float4 per task
    for (int t = blockIdx.x * 256 + threadIdx.x; t < ntask; t += gridDim.x * 256) {
        const int z  = t >> 7;               // 128 tasks per row
        const int u0 = (t & 127) << 2;
        const float4v v = *(const float4v*)(x + (size_t)z * Ud + u0);
        us4 p;
        p[0] = f2bf(v[0]); p[1] = f2bf(v[1]); p[2] = f2bf(v[2]); p[3] = f2bf(v[3]);
        const int tile = (z >> 7) * KT + (u0 >> 6);
        const int off  = tile * TILE_US + sub_off(z & 127, u0 & 63);
        *(us4*)(wsx + off) = p;
    }
}

__global__ __launch_bounds__(256)
void convert_w(const float* __restrict__ w, unsigned short* __restrict__ wsw)
{
    const int ntask = Cg * Ud * Vd / 4;      // 4 k-rows of one column per task
    for (int t = blockIdx.x * 256 + threadIdx.x; t < ntask; t += gridDim.x * 256) {
        const int g   = t >> 16;             // 65536 tasks per group
        const int rem = t & 65535;
        const int u0  = (rem >> 9) << 2;
        const int v   = rem & 511;
        const float* src = w + (size_t)g * (Ud * Vd) + (size_t)u0 * Vd + v;
        us4 p;
        p[0] = f2bf(src[0]);
        p[1] = f2bf(src[Vd]);
        p[2] = f2bf(src[2 * Vd]);
        p[3] = f2bf(src[3 * Vd]);
        const int tile = (g * NBN + (v >> 7)) * KT + (u0 >> 6);
        const int off  = tile * TILE_US + sub_off(v & 127, u0 & 63);
        *(us4*)(wsw + off) = p;
    }
}

// ---------------- GEMM ----------------

__global__ __launch_bounds__(256, 2)
void sgl_gemm(const unsigned short* __restrict__ wsx,
              const unsigned short* __restrict__ wsw,
              const int* __restrict__ idx, const float* __restrict__ coeff,
              float* __restrict__ y)
{
    __shared__ unsigned short As[TILE_US];   // 16 KiB
    __shared__ unsigned short Bs[TILE_US];   // 16 KiB

    const int tid  = threadIdx.x;
    const int bn   = blockIdx.x & (NBN - 1);
    const int bm   = blockIdx.x >> 2;
    const int row0 = bm * BM;
    const int col0 = bn * BN;

    const int lane = tid & 63;
    const int wave = tid >> 6;
    const int l15  = lane & 15;
    const int l4   = lane >> 4;
    const int wr   = (wave >> 1) * 64;
    const int wc   = (wave & 1) * 64;

    const int g_lo = idx[row0];
    const int g_hi = idx[row0 + BM - 1];
    const float cf = coeff[0];

    const unsigned short* xa = wsx + (size_t)(bm * KT) * TILE_US;

    for (int g = g_lo; g <= g_hi; ++g) {     // 1 pass except at group boundaries
        const unsigned short* wb = wsw + (size_t)((g * NBN + bn) * KT) * TILE_US;

        f32x4 acc[4][4];
#pragma unroll
        for (int mi = 0; mi < 4; ++mi)
#pragma unroll
            for (int ni = 0; ni < 4; ++ni)
                acc[mi][ni] = f32x4{0.f, 0.f, 0.f, 0.f};

        for (int kt = 0; kt < KT; ++kt) {
            __syncthreads();                 // prior reads done before overwrite
            // linear 16 KiB copies: 4 instr/wave each for A and B
#pragma unroll
            for (int j = 0; j < 4; ++j) {
                const int o = wave * 2048 + j * 512 + lane * 8;   // ushort offset
                __builtin_amdgcn_global_load_lds(
                    (gbl_uint*)(xa + (size_t)kt * TILE_US + o),
                    (lds_uint*)(As + o), 16, 0, 0);
            }
#pragma unroll
            for (int j = 0; j < 4; ++j) {
                const int o = wave * 2048 + j * 512 + lane * 8;
                __builtin_amdgcn_global_load_lds(
                    (gbl_uint*)(wb + (size_t)kt * TILE_US + o),
                    (lds_uint*)(Bs + o), 16, 0, 0);
            }
            __syncthreads();                 // compiler drains vmcnt before barrier

#pragma unroll
            for (int kk = 0; kk < 2; ++kk) {
                bf16x8 a[4], b[4];
#pragma unroll
                for (int mi = 0; mi < 4; ++mi)
                    a[mi] = *(const bf16x8*)(As + (((wave >> 1) * 4 + mi) << 10)
                                                + ((kk * 4 + l4) << 7) + (l15 << 3));
#pragma unroll
                for (int ni = 0; ni < 4; ++ni)
                    b[ni] = *(const bf16x8*)(Bs + (((wave & 1) * 4 + ni) << 10)
                                                + ((kk * 4 + l4) << 7) + (l15 << 3));
#pragma unroll
                for (int mi = 0; mi < 4; ++mi)
#pragma unroll
                    for (int ni = 0; ni < 4; ++ni)
                        acc[mi][ni] = __builtin_amdgcn_mfma_f32_16x16x32_bf16(
                            a[mi], b[ni], acc[mi][ni], 0, 0, 0);
            }
        }

        // epilogue: C/D layout col=lane&15, row=(lane>>4)*4+q; mask rows to g
#pragma unroll
        for (int mi = 0; mi < 4; ++mi) {
            const int rbase = row0 + wr + mi * 16 + l4 * 4;
            int rok[4];
#pragma unroll
            for (int q = 0; q < 4; ++q) rok[q] = (idx[rbase + q] == g);
#pragma unroll
            for (int ni = 0; ni < 4; ++ni) {
                const int c = col0 + wc + ni * 16 + l15;
#pragma unroll
                for (int q = 0; q < 4; ++q) {
                    if (rok[q]) y[(size_t)(rbase + q) * Vd + c] = acc[mi][ni][q] * cf;
                }
            }
        }
    }
}

// ---------------- fallback (R1 kernel) for small ws ----------------

__global__ __launch_bounds__(256, 2)
void sgl_fallback(const float* __restrict__ w, const float* __restrict__ x,
                  const int* __restrict__ idx, const float* __restrict__ coeff,
                  float* __restrict__ y)
{
    __shared__ unsigned short As[BM * 32];
    __shared__ unsigned short Bs[BN * 32];

    const int tid  = threadIdx.x;
    const int bn   = blockIdx.x & 3;
    const int bm   = blockIdx.x >> 2;
    const int row0 = bm * BM;
    const int col0 = bn * BN;

    const int lane = tid & 63;
    const int wave = tid >> 6;
    const int wr   = (wave >> 1) * 64;
    const int wc   = (wave & 1) * 64;
    const int l15  = lane & 15;
    const int l4   = lane >> 4;

    int ar[4], ak[4], ag[4];
#pragma unroll
    for (int i = 0; i < 4; ++i) {
        int flat = tid + i * 256;
        ar[i] = flat >> 3;
        ak[i] = (flat & 7) << 2;
        ag[i] = idx[row0 + ar[i]];
    }

    const int g_lo = idx[row0];
    const int g_hi = idx[row0 + BM - 1];

    f32x4 acc[4][4];
#pragma unroll
    for (int mi = 0; mi < 4; ++mi)
#pragma unroll
        for (int ni = 0; ni < 4; ++ni)
            acc[mi][ni] = f32x4{0.f, 0.f, 0.f, 0.f};

    for (int g = g_lo; g <= g_hi; ++g) {
        const float* __restrict__ Wg = w + (size_t)g * ((size_t)Ud * Vd);
        for (int kt = 0; kt < 16; ++kt) {
            __syncthreads();
#pragma unroll
            for (int i = 0; i < 4; ++i) {
                const float4v v = *(const float4v*)(x + (size_t)(row0 + ar[i]) * Ud
                                                      + kt * 32 + ak[i]);
                const bool ok = (ag[i] == g);
                us4 p;
                p[0] = f2bf(ok ? v[0] : 0.0f);
                p[1] = f2bf(ok ? v[1] : 0.0f);
                p[2] = f2bf(ok ? v[2] : 0.0f);
                p[3] = f2bf(ok ? v[3] : 0.0f);
                const int off = ((ar[i] >> 4) << 9) | ((ak[i] >> 3) << 7)
                              | ((ar[i] & 15) << 3) | (ak[i] & 7);
                *(us4*)(As + off) = p;
            }
#pragma unroll
            for (int i = 0; i < 4; ++i) {
                const int flat = tid + i * 256;
                const int n  = flat & 127;
                const int k0 = (flat >> 7) << 2;
                const float* src = Wg + (size_t)(kt * 32 + k0) * Vd + col0 + n;
                us4 p;
                p[0] = f2bf(src[0]);
                p[1] = f2bf(src[Vd]);
                p[2] = f2bf(src[2 * Vd]);
                p[3] = f2bf(src[3 * Vd]);
                const int off = ((n >> 4) << 9) | ((k0 >> 3) << 7)
                              | ((n & 15) << 3) | (k0 & 7);
                *(us4*)(Bs + off) = p;
            }
            __syncthreads();
            bf16x8 a[4], b[4];
#pragma unroll
            for (int mi = 0; mi < 4; ++mi)
                a[mi] = *(const bf16x8*)(As + (((wr + mi * 16) >> 4) << 9) + (l4 << 7) + (l15 << 3));
#pragma unroll
            for (int ni = 0; ni < 4; ++ni)
                b[ni] = *(const bf16x8*)(Bs + (((wc + ni * 16) >> 4) << 9) + (l4 << 7) + (l15 << 3));
#pragma unroll
            for (int mi = 0; mi < 4; ++mi)
#pragma unroll
                for (int ni = 0; ni < 4; ++ni)
                    acc[mi][ni] = __builtin_amdgcn_mfma_f32_16x16x32_bf16(
                        a[mi], b[ni], acc[mi][ni], 0, 0, 0);
        }
    }

    const float cf = coeff[0];
#pragma unroll
    for (int mi = 0; mi < 4; ++mi) {
        const int rbase = row0 + wr + mi * 16 + l4 * 4;
#pragma unroll
        for (int ni = 0; ni < 4; ++ni) {
            const int c = col0 + wc + ni * 16 + l15;
#pragma unroll
            for (int q = 0; q < 4; ++q)
                y[(size_t)(rbase + q) * Vd + c] = acc[mi][ni][q] * cf;
        }
    }
}

extern "C" void kernel_launch(void* const* d_in, const int* in_sizes, int n_in,
                              void* d_out, int out_size, void* d_ws, size_t ws_size,
                              hipStream_t stream) {
    const float* w     = (const float*)d_in[0];
    const float* x     = (const float*)d_in[1];
    const int*   idx   = (const int*)d_in[2];
    const float* coeff = (const float*)d_in[3];
    float* y = (float*)d_out;

    if (ws_size >= WS_NEEDED) {
        unsigned short* wsx = (unsigned short*)d_ws;
        unsigned short* wsw = wsx + (size_t)WSX_TILES * TILE_US;
        hipLaunchKernelGGL(convert_x, dim3(4096), dim3(256), 0, stream, x, wsx);
        hipLaunchKernelGGL(convert_w, dim3(2048), dim3(256), 0, stream, w, wsw);
        hipLaunchKernelGGL(sgl_gemm, dim3(NBM * NBN), dim3(256), 0, stream,
                           wsx, wsw, idx, coeff, y);
    } else {
        hipLaunchKernelGGL(sgl_fallback, dim3(NBM * NBN), dim3(256), 0, stream,
                           w, x, idx, coeff, y);
    }
}

// Round 3
// 67.883 us; speedup vs baseline: 1.0688x; 1.0386x over previous
//
#include <hip/hip_runtime.h>
#include <stdint.h>

// Grouped linear: y[z] = coeff * x[z] @ W[idx[z]], idx sorted.
// C=8, U=V=512, Z=32768, fp32 in/out, bf16 MFMA compute.
//
// R3: one merged converter kernel writes bf16 pre-tiled copies of x and W^T
// into d_ws; GEMM is 256x256 tile, 8 waves, BK=32, 2-phase LDS double-buffer
// (stage-next-before-compute, one barrier per K-step), global_load_lds
// staging, conflict-free subtiled ds_read_b128, XCD-chunked block swizzle.

#define Cg 8
#define Ud 512
#define Vd 512
#define Zd 32768

#define BM 256
#define BN 256
#define BK 32
#define KT (Ud / BK)            // 16
#define TILE_US (BM * BK)       // 8192 ushorts = 16 KiB

#define NBM (Zd / BM)           // 128
#define NBN (Vd / BN)           // 2
#define WSX_TILES (NBM * KT)                 // 2048 tiles = 32 MiB
#define WSW_TILES (Cg * NBN * KT)            // 256 tiles  =  4 MiB
#define WS_NEEDED ((size_t)(WSX_TILES + WSW_TILES) * TILE_US * 2)

#define NXTASK (Zd * Ud / 8)    // 2,097,152 (one us8 per task)
#define NWTASK (Cg * Ud * Vd / 4)

typedef __attribute__((ext_vector_type(8))) short bf16x8;
typedef __attribute__((ext_vector_type(4))) float f32x4;
typedef __attribute__((ext_vector_type(4))) unsigned short us4;
typedef __attribute__((ext_vector_type(8))) unsigned short us8;
typedef __attribute__((ext_vector_type(4))) float float4v;

typedef __attribute__((address_space(3))) unsigned int lds_uint;
typedef const __attribute__((address_space(1))) unsigned int gbl_uint;

__device__ __forceinline__ unsigned short f2bf(float f) {
    unsigned int u = __float_as_uint(f);
    u += 0x7fffu + ((u >> 16) & 1u);   // round-to-nearest-even
    return (unsigned short)(u >> 16);
}

// Subtile layout within one [256 rows][32 k] tile (ushort offset):
//   (r>>4)*512 + (k>>3)*128 + (r&15)*8 + (k&7)
// Fragment read (16x16x32 MFMA, lane l): r=l&15(+16*rt), k=(l>>4)*8 ->
// byte = rt*1024 + l4*256 + l15*16: 16-lane groups cover 32 banks, 2-way
// aliasing only (free) -> conflict-free ds_read_b128.
__device__ __forceinline__ int sub32(int r, int k) {
    return ((r >> 4) << 9) + ((k >> 3) << 7) + ((r & 15) << 3) + (k & 7);
}

// ---------------- merged converter ----------------

__global__ __launch_bounds__(256)
void convert_all(const float* __restrict__ x, const float* __restrict__ w,
                 unsigned short* __restrict__ wsx, unsigned short* __restrict__ wsw)
{
    const int stride = gridDim.x * 256;
    for (int t = blockIdx.x * 256 + threadIdx.x; t < NXTASK + NWTASK; t += stride) {
        if (t < NXTASK) {
            // x: thread handles 8 consecutive u of one z (32B read, 16B write)
            const int z  = t >> 6;               // 64 tasks per row
            const int u0 = (t & 63) << 3;
            const float* src = x + (size_t)z * Ud + u0;
            const float4v v0 = *(const float4v*)(src);
            const float4v v1 = *(const float4v*)(src + 4);
            us8 p;
            p[0] = f2bf(v0[0]); p[1] = f2bf(v0[1]); p[2] = f2bf(v0[2]); p[3] = f2bf(v0[3]);
            p[4] = f2bf(v1[0]); p[5] = f2bf(v1[1]); p[6] = f2bf(v1[2]); p[7] = f2bf(v1[3]);
            const int tile = ((z >> 8) << 4) + (u0 >> 5);
            const int off  = tile * TILE_US + sub32(z & 255, u0 & 31);
            *(us8*)(wsx + off) = p;
        } else {
            // w: thread handles 4 k-rows of one output column v (transpose)
            const int tw  = t - NXTASK;
            const int g   = tw >> 16;            // 65536 tasks per group
            const int rem = tw & 65535;
            const int u0  = (rem >> 9) << 2;
            const int v   = rem & 511;
            const float* src = w + (size_t)g * (Ud * Vd) + (size_t)u0 * Vd + v;
            us4 p;
            p[0] = f2bf(src[0]);
            p[1] = f2bf(src[Vd]);
            p[2] = f2bf(src[2 * Vd]);
            p[3] = f2bf(src[3 * Vd]);
            const int tile = ((g * 2 + (v >> 8)) << 4) + (u0 >> 5);
            const int off  = tile * TILE_US + sub32(v & 255, u0 & 31);
            *(us4*)(wsw + off) = p;
        }
    }
}

// ---------------- GEMM: 256x256, 8 waves, 2-phase dbuf ----------------

#define STAGE(AS, BS, asrc, bsrc) do {                                        \
    _Pragma("unroll")                                                         \
    for (int j_ = 0; j_ < 2; ++j_) {                                          \
        const int o_ = tid * 8 + j_ * 4096;                                   \
        __builtin_amdgcn_global_load_lds((gbl_uint*)((asrc) + o_),            \
                                         (lds_uint*)(AS + o_), 16, 0, 0);     \
        __builtin_amdgcn_global_load_lds((gbl_uint*)((bsrc) + o_),            \
                                         (lds_uint*)(BS + o_), 16, 0, 0);     \
    } } while (0)

#define COMPUTE(AS, BS) do {                                                  \
    bf16x8 a_[8], b_[4];                                                      \
    _Pragma("unroll")                                                         \
    for (int mi_ = 0; mi_ < 8; ++mi_)                                         \
        a_[mi_] = *(const bf16x8*)(AS + ((art + mi_) << 9) + koff);           \
    _Pragma("unroll")                                                         \
    for (int ni_ = 0; ni_ < 4; ++ni_)                                         \
        b_[ni_] = *(const bf16x8*)(BS + ((brt + ni_) << 9) + koff);           \
    _Pragma("unroll")                                                         \
    for (int mi_ = 0; mi_ < 8; ++mi_)                                         \
        _Pragma("unroll")                                                     \
        for (int ni_ = 0; ni_ < 4; ++ni_)                                     \
            acc[mi_][ni_] = __builtin_amdgcn_mfma_f32_16x16x32_bf16(          \
                a_[mi_], b_[ni_], acc[mi_][ni_], 0, 0, 0);                    \
    } while (0)

__global__ __launch_bounds__(512, 2)
void sgl_gemm(const unsigned short* __restrict__ wsx,
              const unsigned short* __restrict__ wsw,
              const int* __restrict__ idx, const float* __restrict__ coeff,
              float* __restrict__ y)
{
    __shared__ unsigned short As0[TILE_US], As1[TILE_US];
    __shared__ unsigned short Bs0[TILE_US], Bs1[TILE_US];   // 64 KiB total

    const int tid = threadIdx.x;
    // XCD-chunked swizzle: XCD x = bid%8 gets contiguous work chunk [32x,32x+32)
    // -> bm in [16x,16x+16), both bn halves on same XCD (wsx L2 reuse).
    const int wk  = ((blockIdx.x & 7) << 5) | (blockIdx.x >> 3);
    const int bm  = wk >> 1;
    const int bn  = wk & 1;
    const int row0 = bm * BM;
    const int col0 = bn * BN;

    const int lane = tid & 63, wave = tid >> 6;
    const int l15 = lane & 15, l4 = lane >> 4;
    const int wrow = (wave >> 2) * 128;       // 2 wave-rows of 128
    const int wcol = (wave & 3) * 64;         // 4 wave-cols of 64
    const int art  = (wrow >> 4);             // A row-tile base (0 or 8)
    const int brt  = (wcol >> 4);             // B row-tile base (0,4,8,12)
    const int koff = (l4 << 7) + (l15 << 3);  // ushort offset within subtile

    const int g_lo = idx[row0];
    const int g_hi = idx[row0 + BM - 1];
    const float cf = coeff[0];

    const unsigned short* xa = wsx + (size_t)bm * (KT * TILE_US);

    for (int g = g_lo; g <= g_hi; ++g) {      // 1 pass except boundary tiles
        const unsigned short* wb = wsw + (size_t)((g * NBN + bn) * KT) * TILE_US;

        f32x4 acc[8][4];
#pragma unroll
        for (int mi = 0; mi < 8; ++mi)
#pragma unroll
            for (int ni = 0; ni < 4; ++ni)
                acc[mi][ni] = f32x4{0.f, 0.f, 0.f, 0.f};

        STAGE(As0, Bs0, xa, wb);
        __syncthreads();                      // drain prologue loads
#pragma unroll 1
        for (int kt = 0; kt < KT; kt += 2) {
            if (kt + 1 < KT)
                STAGE(As1, Bs1, xa + (kt + 1) * TILE_US, wb + (kt + 1) * TILE_US);
            COMPUTE(As0, Bs0);
            __syncthreads();                  // drains vmcnt; As1/Bs1 ready
            if (kt + 2 < KT)
                STAGE(As0, Bs0, xa + (kt + 2) * TILE_US, wb + (kt + 2) * TILE_US);
            COMPUTE(As1, Bs1);
            __syncthreads();
        }

        // epilogue: C/D layout col=lane&15, row=(lane>>4)*4+q; mask rows to g
        const bool multi = (g_lo != g_hi);
#pragma unroll
        for (int mi = 0; mi < 8; ++mi) {
            const int rbase = row0 + wrow + mi * 16 + l4 * 4;
            bool ok[4];
#pragma unroll
            for (int q = 0; q < 4; ++q)
                ok[q] = !multi || (idx[rbase + q] == g);
#pragma unroll
            for (int ni = 0; ni < 4; ++ni) {
                const int c = col0 + wcol + ni * 16 + l15;
#pragma unroll
                for (int q = 0; q < 4; ++q)
                    if (ok[q]) y[(size_t)(rbase + q) * Vd + c] = acc[mi][ni][q] * cf;
            }
        }
    }
}

// ---------------- safety-net fallback (ws too small; not expected) --------

__global__ __launch_bounds__(256)
void sgl_naive(const float* __restrict__ w, const float* __restrict__ x,
               const int* __restrict__ idx, const float* __restrict__ coeff,
               float* __restrict__ y)
{
    __shared__ float xs[Ud];
    const int z = blockIdx.x;
    const int g = idx[z];
    for (int u = threadIdx.x; u < Ud; u += 256) xs[u] = x[(size_t)z * Ud + u];
    __syncthreads();
    const float* Wg = w + (size_t)g * (Ud * Vd);
    const float cf = coeff[0];
    for (int v = threadIdx.x; v < Vd; v += 256) {
        float acc = 0.f;
        for (int u = 0; u < Ud; ++u) acc += xs[u] * Wg[(size_t)u * Vd + v];
        y[(size_t)z * Vd + v] = acc * cf;
    }
}

extern "C" void kernel_launch(void* const* d_in, const int* in_sizes, int n_in,
                              void* d_out, int out_size, void* d_ws, size_t ws_size,
                              hipStream_t stream) {
    const float* w     = (const float*)d_in[0];
    const float* x     = (const float*)d_in[1];
    const int*   idx   = (const int*)d_in[2];
    const float* coeff = (const float*)d_in[3];
    float* y = (float*)d_out;

    if (ws_size >= WS_NEEDED) {
        unsigned short* wsx = (unsigned short*)d_ws;
        unsigned short* wsw = wsx + (size_t)WSX_TILES * TILE_US;
        hipLaunchKernelGGL(convert_all, dim3(2048), dim3(256), 0, stream,
                           x, w, wsx, wsw);
        hipLaunchKernelGGL(sgl_gemm, dim3(NBM * NBN), dim3(512), 0, stream,
                           wsx, wsw, idx, coeff, y);
    } else {
        hipLaunchKernelGGL(sgl_naive, dim3(Zd), dim3(256), 0, stream,
                           w, x, idx, coeff, y);
    }
}

// Round 4
// 64.444 us; speedup vs baseline: 1.1258x; 1.0534x over previous
//
#include <hip/hip_runtime.h>
#include <stdint.h>

// Grouped linear: y[z] = coeff * x[z] @ W[idx[z]], idx sorted.
// C=8, U=V=512, Z=32768, fp32 in/out, bf16 MFMA compute.
//
// R4: single-pass x (reg-staged fp32->bf16 inside GEMM, read once from HBM);
// w pre-converted/pre-tiled to bf16 in d_ws (cheap) + group starts[] there.
// Group-padded row blocks (every block single-group), 128x128 tile, BK=32,
// 4 waves, 3 blocks/CU, 2-phase LDS double-buffer with early A-loads,
// lane-linear ds_write/global_load_lds, conflict-free subtiled ds_read_b128,
// bijective XCD swizzle.

#define Cg 8
#define Ud 512
#define Vd 512
#define Zd 32768

#define BM 128
#define BN 128
#define BK 32
#define KT 16                    // 512 / 32

#define ATILE_US 4096            // 128*32 bf16 = 8 KiB
#define BTILE_US 4096
#define NBN 4
#define NBM_MAX 263              // sum ceil(cnt_g/128) <= 256+7
#define GRID_GEMM (NBM_MAX * NBN)   // 1052

#define WSW_US (Cg * NBN * KT * BTILE_US)        // 2,097,152 us = 4 MiB
#define WS_NEEDED ((size_t)WSW_US * 2 + 64)

typedef __attribute__((ext_vector_type(8))) short bf16x8;
typedef __attribute__((ext_vector_type(4))) float f32x4;
typedef __attribute__((ext_vector_type(4))) unsigned short us4;
typedef __attribute__((ext_vector_type(4))) float float4v;
typedef __attribute__((ext_vector_type(4))) unsigned int u32x4;

typedef __attribute__((address_space(3))) unsigned int lds_uint;
typedef const __attribute__((address_space(1))) unsigned int gbl_uint;

__device__ __forceinline__ unsigned short f2bf(float f) {
    unsigned int u = __float_as_uint(f);
    u += 0x7fffu + ((u >> 16) & 1u);   // round-to-nearest-even
    return (unsigned short)(u >> 16);
}
__device__ __forceinline__ unsigned int pk2(float lo, float hi) {
    return (unsigned int)f2bf(lo) | ((unsigned int)f2bf(hi) << 16);
}

// Subtile layout within one [128 r][32 k] tile (ushort offset):
//   (r>>4)*512 + (k>>3)*128 + (r&15)*8 + (k&7)
// Frag read (lane l): byte = rt*1024 + l4*256 + l15*16 -> conflict-free b128.

// ---------------- w converter (+ group starts) ----------------

__global__ __launch_bounds__(256)
void convert_w(const float* __restrict__ w, const int* __restrict__ idx,
               unsigned short* __restrict__ wsw, int* __restrict__ starts)
{
    const int t = blockIdx.x * 256 + threadIdx.x;    // 524288 tasks, 1 each
    const int g   = t >> 16;                          // 65536 tasks/group
    const int rem = t & 65535;
    const int u0  = (rem >> 9) << 2;                  // 4 k-rows
    const int v   = rem & 511;
    const float* src = w + ((size_t)g << 18) + (size_t)u0 * Vd + v;
    us4 p;
    p[0] = f2bf(src[0]);
    p[1] = f2bf(src[Vd]);
    p[2] = f2bf(src[2 * Vd]);
    p[3] = f2bf(src[3 * Vd]);
    const int r = v & 127, k = u0 & 31;
    const int tile = (g * NBN + (v >> 7)) * KT + (u0 >> 5);
    const int off  = tile * BTILE_US
                   + ((r >> 4) << 9) + ((k >> 3) << 7) + ((r & 15) << 3) + (k & 7);
    *(us4*)(wsw + off) = p;

    if (blockIdx.x == 0 && threadIdx.x < 9) {
        const int gq = threadIdx.x;
        int lo = 0;
        if (gq >= 8) lo = Zd;
        else {
            int hi = Zd;
            while (lo < hi) { int mid = (lo + hi) >> 1;
                              if (idx[mid] < gq) lo = mid + 1; else hi = mid; }
        }
        starts[gq] = lo;
    }
}

// ---------------- GEMM ----------------

#define LOADA(KTV, Q0, Q1, Q2, Q3) do {                                       \
    const float4v z_ = float4v{0.f, 0.f, 0.f, 0.f};                           \
    Q0 = v0 ? *(const float4v*)(a0 + (KTV) * BK)     : z_;                    \
    Q1 = v0 ? *(const float4v*)(a0 + (KTV) * BK + 4) : z_;                    \
    Q2 = v1 ? *(const float4v*)(a1 + (KTV) * BK)     : z_;                    \
    Q3 = v1 ? *(const float4v*)(a1 + (KTV) * BK + 4) : z_;                    \
  } while (0)

#define CVTW(AS, Q0, Q1, Q2, Q3) do {                                         \
    u32x4 t0_, t1_;                                                           \
    t0_[0] = pk2(Q0[0], Q0[1]); t0_[1] = pk2(Q0[2], Q0[3]);                   \
    t0_[2] = pk2(Q1[0], Q1[1]); t0_[3] = pk2(Q1[2], Q1[3]);                   \
    t1_[0] = pk2(Q2[0], Q2[1]); t1_[1] = pk2(Q2[2], Q2[3]);                   \
    t1_[2] = pk2(Q3[0], Q3[1]); t1_[3] = pk2(Q3[2], Q3[3]);                   \
    *(u32x4*)(AS + aw0) = t0_;                                                \
    *(u32x4*)(AS + aw1) = t1_;                                                \
  } while (0)

#define GLOADB(KTV, BS) do {                                                  \
    const unsigned short* s_ = wB + (size_t)(KTV) * BTILE_US;                 \
    __builtin_amdgcn_global_load_lds((gbl_uint*)(s_ + bo0),                   \
                                     (lds_uint*)(BS + bo0), 16, 0, 0);        \
    __builtin_amdgcn_global_load_lds((gbl_uint*)(s_ + bo1),                   \
                                     (lds_uint*)(BS + bo1), 16, 0, 0);        \
  } while (0)

#define COMPUTE(AS, BS) do {                                                  \
    bf16x8 a_[4];                                                             \
    _Pragma("unroll")                                                         \
    for (int mi_ = 0; mi_ < 4; ++mi_)                                         \
        a_[mi_] = *(const bf16x8*)(AS + ((wm4 + mi_) << 9) + fr);             \
    _Pragma("unroll")                                                         \
    for (int ni_ = 0; ni_ < 4; ++ni_) {                                       \
        const bf16x8 b_ = *(const bf16x8*)(BS + ((wn4 + ni_) << 9) + fr);     \
        _Pragma("unroll")                                                     \
        for (int mi_ = 0; mi_ < 4; ++mi_)                                     \
            acc[mi_][ni_] = __builtin_amdgcn_mfma_f32_16x16x32_bf16(          \
                a_[mi_], b_, acc[mi_][ni_], 0, 0, 0);                         \
    } } while (0)

__global__ __launch_bounds__(256, 3)
void sgl_gemm(const float* __restrict__ x,
              const unsigned short* __restrict__ wsw,
              const int* __restrict__ starts,
              const float* __restrict__ coeff,
              float* __restrict__ y)
{
    __shared__ unsigned short As0[ATILE_US], Bs0[BTILE_US];
    __shared__ unsigned short As1[ATILE_US], Bs1[BTILE_US];   // 32 KiB

    const int tid = threadIdx.x, lane = tid & 63, wave = tid >> 6;
    const int l15 = lane & 15, l4 = lane >> 4;

    // bijective XCD swizzle: nwg=1052, q=131, r=4 (m204)
    const int orig = blockIdx.x;
    const int xcd = orig & 7, io = orig >> 3;
    const int wk = (xcd < 4) ? xcd * 132 + io : 528 + (xcd - 4) * 131 + io;
    const int bmp = wk >> 2;
    const int bn  = wk & 3;

    // locate group for this padded row-block
    int s[9];
#pragma unroll
    for (int i = 0; i < 9; ++i) s[i] = starts[i];
    int g = -1, lblk = 0, ab = 0;
#pragma unroll
    for (int gg = 0; gg < 8; ++gg) {
        const int c  = s[gg + 1] - s[gg];
        const int nb = (c + BM - 1) >> 7;
        if (g < 0 && bmp < ab + nb) { g = gg; lblk = bmp - ab; }
        ab += nb;
    }
    if (g < 0) return;                         // beyond padded total
    const int start = s[g];
    const int cnt   = s[g + 1] - s[g];
    const int j0    = lblk << 7;

    // A staging: wave covers rows [w*32, w*32+32), lane-linear LDS writes.
    // lane L -> rows r0=w*32+l15, r1=r0+16; k-segment cA = (L>>5)*16 + ((L>>4)&1)*8
    const int cA = ((lane >> 5) << 4) + (((lane >> 4) & 1) << 3);
    const int r0 = wave * 32 + l15;
    const int r1 = r0 + 16;
    const bool v0 = (j0 + r0) < cnt;
    const bool v1 = (j0 + r1) < cnt;
    const float* a0 = x + (size_t)(start + j0 + r0) * Ud + cA;
    const float* a1 = x + (size_t)(start + j0 + r1) * Ud + cA;
    const int aw0 = wave * 1024 + lane * 8;    // us; == rt*512 + lane*8
    const int aw1 = aw0 + 512;

    // B staging: linear 8 KiB tile, 2 x global_load_lds per thread
    const unsigned short* wB = wsw + (size_t)((g * NBN + bn) * KT) * BTILE_US;
    const int bo0 = wave * 1024 + lane * 8;
    const int bo1 = bo0 + 512;

    const int wm4 = (wave >> 1) << 2;          // A row-tile base
    const int wn4 = (wave & 1) << 2;           // B row-tile base
    const int fr  = (l4 << 7) + (l15 << 3);

    f32x4 acc[4][4];
#pragma unroll
    for (int mi = 0; mi < 4; ++mi)
#pragma unroll
        for (int ni = 0; ni < 4; ++ni)
            acc[mi][ni] = f32x4{0.f, 0.f, 0.f, 0.f};

    float4v e0, e1, e2, e3;                    // even-tile raw A
    float4v o0, o1, o2, o3;                    // odd-tile raw A

    // prologue: tiles 0 and 1
    LOADA(0, e0, e1, e2, e3);
    GLOADB(0, Bs0);
    CVTW(As0, e0, e1, e2, e3);
    LOADA(1, o0, o1, o2, o3);
    GLOADB(1, Bs1);
    __syncthreads();                           // tile 0 (and 1's B) ready

#pragma unroll
    for (int it = 0; it < 8; ++it) {
        const int kt = it * 2;
        CVTW(As1, o0, o1, o2, o3);             // tile kt+1 -> buf1
        if (kt + 2 < KT) LOADA(kt + 2, e0, e1, e2, e3);
        COMPUTE(As0, Bs0);                     // tile kt
        __syncthreads();                       // tile kt+1 ready; buf0 free
        if (kt + 2 < KT) { GLOADB(kt + 2, Bs0); CVTW(As0, e0, e1, e2, e3); }
        if (kt + 3 < KT) LOADA(kt + 3, o0, o1, o2, o3);
        COMPUTE(As1, Bs1);                     // tile kt+1
        __syncthreads();                       // tile kt+2 ready; buf1 free
        if (kt + 3 < KT) GLOADB(kt + 3, Bs1);
    }

    // epilogue: C/D layout col=lane&15, row=(lane>>4)*4+q; mask padded rows
    const float cf = coeff[0];
    const bool full = (j0 + BM) <= cnt;
#pragma unroll
    for (int mi = 0; mi < 4; ++mi) {
        const int rb = ((wave >> 1) << 6) + mi * 16 + l4 * 4;   // row in tile
#pragma unroll
        for (int ni = 0; ni < 4; ++ni) {
            const int c = bn * BN + ((wave & 1) << 6) + ni * 16 + l15;
#pragma unroll
            for (int q = 0; q < 4; ++q) {
                if (full || (j0 + rb + q) < cnt)
                    y[(size_t)(start + j0 + rb + q) * Vd + c] = acc[mi][ni][q] * cf;
            }
        }
    }
}

// ---------------- safety-net fallback (ws too small; not expected) --------

__global__ __launch_bounds__(256)
void sgl_naive(const float* __restrict__ w, const float* __restrict__ x,
               const int* __restrict__ idx, const float* __restrict__ coeff,
               float* __restrict__ y)
{
    __shared__ float xs[Ud];
    const int z = blockIdx.x;
    const int g = idx[z];
    for (int u = threadIdx.x; u < Ud; u += 256) xs[u] = x[(size_t)z * Ud + u];
    __syncthreads();
    const float* Wg = w + (size_t)g * (Ud * Vd);
    const float cf = coeff[0];
    for (int v = threadIdx.x; v < Vd; v += 256) {
        float acc = 0.f;
        for (int u = 0; u < Ud; ++u) acc += xs[u] * Wg[(size_t)u * Vd + v];
        y[(size_t)z * Vd + v] = acc * cf;
    }
}

extern "C" void kernel_launch(void* const* d_in, const int* in_sizes, int n_in,
                              void* d_out, int out_size, void* d_ws, size_t ws_size,
                              hipStream_t stream) {
    const float* w     = (const float*)d_in[0];
    const float* x     = (const float*)d_in[1];
    const int*   idx   = (const int*)d_in[2];
    const float* coeff = (const float*)d_in[3];
    float* y = (float*)d_out;

    if (ws_size >= WS_NEEDED) {
        unsigned short* wsw = (unsigned short*)d_ws;
        int* starts = (int*)((char*)d_ws + (size_t)WSW_US * 2);
        hipLaunchKernelGGL(convert_w, dim3(2048), dim3(256), 0, stream,
                           w, idx, wsw, starts);
        hipLaunchKernelGGL(sgl_gemm, dim3(GRID_GEMM), dim3(256), 0, stream,
                           x, wsw, starts, coeff, y);
    } else {
        hipLaunchKernelGGL(sgl_naive, dim3(Zd), dim3(256), 0, stream,
                           w, x, idx, coeff, y);
    }
}